// Round 3
// baseline (382.281 us; speedup 1.0000x reference)
//
#include <hip/hip_runtime.h>

// cdist(x1, x2) on MI355X: d[i][j] = sqrt(||x1_i||^2 + ||x2_j||^2 - 2*x1_i.x2_j)
// R3: barrier-free, LDS-free MFMA GEMM.
// Regime: K=256 -> 34.4 GFLOP vs 256 MiB stores -> STORE-bound (needs only
// ~35% MfmaUtil). R0/R2 post-mortem: the 2-barrier staged loop caps ~600 TF
// steady-state (m233) and short-K exposes its prologue/epilogue -> 141-171us.
// A+B are 8 MiB bf16 (L2-resident; ~3 MiB per XCD chunk) so LDS staging buys
// nothing (common-mistake #7). Each wave owns a 64x64 tile, loads MFMA
// fragments straight from L2 (16B/lane contiguous), explicit 2-deep register
// double-buffer, zero __syncthreads, nontemporal stores.

typedef __bf16 v8bf __attribute__((ext_vector_type(8)));
typedef float v4f __attribute__((ext_vector_type(4)));

#define NROWS 8192
#define KDIM  256

__device__ __forceinline__ ushort f2bf_rne(float f) {
    union { float f; unsigned u; } a; a.f = f;
    unsigned u = a.u + 0x7fffu + ((a.u >> 16) & 1u);  // round-to-nearest-even
    return (ushort)(u >> 16);
}

// One wave per row: load 256 floats as float4/lane, emit bf16 row + fp32 norm.
// Merged: first 2048 blocks process x1, rest x2 (saves a launch).
__global__ __launch_bounds__(256) void cvt_norm_kernel(
    const float* __restrict__ x1, const float* __restrict__ x2,
    ushort* __restrict__ xb1, ushort* __restrict__ xb2,
    float* __restrict__ sq1, float* __restrict__ sq2) {
    const int half2 = NROWS / 4;  // 2048 blocks per input
    const float* x = (blockIdx.x < half2) ? x1 : x2;
    ushort* xb     = (blockIdx.x < half2) ? xb1 : xb2;
    float* sq      = (blockIdx.x < half2) ? sq1 : sq2;
    const int bb   = (blockIdx.x < half2) ? blockIdx.x : blockIdx.x - half2;

    const int wave = threadIdx.x >> 6;
    const int lane = threadIdx.x & 63;
    const int row  = bb * 4 + wave;
    const float4 v = ((const float4*)(x + (size_t)row * KDIM))[lane];
    float s = v.x * v.x + v.y * v.y + v.z * v.z + v.w * v.w;
#pragma unroll
    for (int off = 32; off; off >>= 1) s += __shfl_down(s, off);
    if (lane == 0) sq[row] = s;
    ushort4 o;
    o.x = f2bf_rne(v.x); o.y = f2bf_rne(v.y);
    o.z = f2bf_rne(v.z); o.w = f2bf_rne(v.w);
    ((ushort4*)(xb + (size_t)row * KDIM))[lane] = o;
}

__global__ __launch_bounds__(256) void cdist_nobar_kernel(
    const ushort* __restrict__ A,    // x1 bf16, [8192][256]
    const ushort* __restrict__ B,    // x2 bf16, [8192][256]
    const float* __restrict__ sq1,   // ||x1_i||^2
    const float* __restrict__ sq2,   // ||x2_j||^2
    float* __restrict__ out) {       // [8192][8192]
    // Block = 128x128 tile (2x2 waves x 64x64 each). Grid 4096 blocks.
    // XCD chunking: 8 chunks of 16(bm) x 32(bn) tiles; per-XCD working set
    // A 1 MiB + B 2 MiB = 3 MiB < 4 MiB L2. Bijective (4096 % 8 == 0).
    const int bid = blockIdx.x;
    const int xcd = bid & 7;
    const int cc  = bid >> 3;                     // 0..511
    const int bm  = ((xcd & 3) << 4) | (cc & 15); // 0..63
    const int bn  = ((xcd >> 2) << 5) | (cc >> 4);// 0..63

    const int wave = threadIdx.x >> 6;
    const int lane = threadIdx.x & 63;
    const int wr = wave >> 1, wc = wave & 1;
    const int mrow = lane & 15;       // fragment row/col within 16
    const int half = lane >> 4;       // 0..3 -> k sub-offset half*8

    const int m0 = bm * 128 + wr * 64;
    const int n0 = bn * 128 + wc * 64;

    // Per-fragment global base pointers (16B/lane contiguous loads, same
    // lane->element mapping as the verified LDS-read pattern: row = mrow,
    // k = kk + half*8 .. +8).
    const ushort* Ap[4];
    const ushort* Bp[4];
#pragma unroll
    for (int i = 0; i < 4; ++i) {
        Ap[i] = A + (size_t)(m0 + i * 16 + mrow) * KDIM + half * 8;
        Bp[i] = B + (size_t)(n0 + i * 16 + mrow) * KDIM + half * 8;
    }

    v4f acc[4][4];
#pragma unroll
    for (int i = 0; i < 4; ++i)
#pragma unroll
        for (int j = 0; j < 4; ++j) acc[i][j] = (v4f){0.f, 0.f, 0.f, 0.f};

    // Register double-buffer over the 8 kk-steps (K=256, 32 per MFMA).
    // All indices compile-time constant under full unroll (rule #20).
    v8bf a[2][4], b[2][4];
#pragma unroll
    for (int i = 0; i < 4; ++i) {
        a[0][i] = *(const v8bf*)Ap[i];
        b[0][i] = *(const v8bf*)Bp[i];
    }
#pragma unroll
    for (int t = 0; t < 8; ++t) {
        const int cur = t & 1, nxt = cur ^ 1;
        if (t < 7) {
#pragma unroll
            for (int i = 0; i < 4; ++i) {
                a[nxt][i] = *(const v8bf*)(Ap[i] + (t + 1) * 32);
                b[nxt][i] = *(const v8bf*)(Bp[i] + (t + 1) * 32);
            }
        }
#pragma unroll
        for (int i = 0; i < 4; ++i)
#pragma unroll
            for (int j = 0; j < 4; ++j)
                acc[i][j] = __builtin_amdgcn_mfma_f32_16x16x32_bf16(
                    a[cur][i], b[cur][j], acc[i][j], 0, 0, 0);
    }

    // Epilogue: C/D layout col=lane&15, row=(lane>>4)*4+reg (m89/m91 verified).
    // Nontemporal stores: output is write-once; keep L2 for A/B (now on the
    // per-kk critical load path).
    float s2v[4];
#pragma unroll
    for (int j = 0; j < 4; ++j) s2v[j] = sq2[n0 + j * 16 + mrow];
#pragma unroll
    for (int i = 0; i < 4; ++i) {
        const int rbase = m0 + i * 16 + half * 4;
        float s1v[4];
#pragma unroll
        for (int r = 0; r < 4; ++r) s1v[r] = sq1[rbase + r];
#pragma unroll
        for (int r = 0; r < 4; ++r) {
            float* op = out + (size_t)(rbase + r) * NROWS + n0 + mrow;
#pragma unroll
            for (int j = 0; j < 4; ++j) {
                const float d2 = s1v[r] + s2v[j] - 2.0f * acc[i][j][r];
                __builtin_nontemporal_store(sqrtf(fmaxf(d2, 0.0f)), op + j * 16);
            }
        }
    }
}

extern "C" void kernel_launch(void* const* d_in, const int* in_sizes, int n_in,
                              void* d_out, int out_size, void* d_ws, size_t ws_size,
                              hipStream_t stream) {
    const float* x1 = (const float*)d_in[0];
    const float* x2 = (const float*)d_in[1];
    float* out = (float*)d_out;

    // ws layout: A_bf16 (4 MiB) | B_bf16 (4 MiB) | sq1 (32 KiB) | sq2 (32 KiB)
    ushort* Ab = (ushort*)d_ws;
    ushort* Bb = Ab + (size_t)NROWS * KDIM;
    float* sq1 = (float*)(Bb + (size_t)NROWS * KDIM);
    float* sq2 = sq1 + NROWS;

    cvt_norm_kernel<<<NROWS / 2, 256, 0, stream>>>(x1, x2, Ab, Bb, sq1, sq2);

    // (8192/128)^2 = 4096 blocks, XCD-chunked inside the kernel.
    cdist_nobar_kernel<<<4096, 256, 0, stream>>>(Ab, Bb, sq1, sq2, out);
}

// Round 4
// 314.703 us; speedup vs baseline: 1.2147x; 1.2147x over previous
//
#include <hip/hip_runtime.h>

// cdist(x1, x2) on MI355X: d[i][j] = sqrt(||x1_i||^2 + ||x2_j||^2 - 2*x1_i.x2_j)
// R4: back to R0's proven 128x128 LDS-staged structure (best measured, ~141us
// cdist), with the latency exposure attacked via TLP:
//  - 8 waves/block (wave tile 64x32, acc[4][2]) -> VGPR ~80 -> 3 blocks/CU at
//    6 waves/SIMD (2x R0's 3/SIMD). Same per-K-step economics as m97.
//  - plain stores (R3 counters: nontemporal caused 344 vs 256 MiB writes).
//  - XCD-chunked grid (FETCH=12.7MB confirmed inputs L2-resident).
// Roofline: stores 256 MiB ~43us; compute 14us; tile traffic 30us of L2.

typedef __bf16 v8bf __attribute__((ext_vector_type(8)));
typedef float v4f __attribute__((ext_vector_type(4)));

#define NROWS 8192
#define KDIM  256
#define TILE  128
#define BK    64
#define NTHREADS 512

typedef const __attribute__((address_space(1))) ushort* gas_ushort_p;
typedef __attribute__((address_space(3))) ushort* las_ushort_p;

__device__ __forceinline__ void async_load16(const ushort* g, ushort* l) {
    // global -> LDS direct DMA, 16B per lane. LDS dest is wave-uniform base +
    // lane*16 (hardware uses first lane's lds address).
    __builtin_amdgcn_global_load_lds((gas_ushort_p)g, (las_ushort_p)l, 16, 0, 0);
}

__device__ __forceinline__ ushort f2bf_rne(float f) {
    union { float f; unsigned u; } a; a.f = f;
    unsigned u = a.u + 0x7fffu + ((a.u >> 16) & 1u);  // round-to-nearest-even
    return (ushort)(u >> 16);
}

// One wave per row: load 256 floats as float4/lane, emit bf16 row + fp32 norm.
// Merged: first 2048 blocks process x1, rest x2.
__global__ __launch_bounds__(256) void cvt_norm_kernel(
    const float* __restrict__ x1, const float* __restrict__ x2,
    ushort* __restrict__ xb1, ushort* __restrict__ xb2,
    float* __restrict__ sq1, float* __restrict__ sq2) {
    const int half2 = NROWS / 4;  // 2048 blocks per input
    const float* x = (blockIdx.x < half2) ? x1 : x2;
    ushort* xb     = (blockIdx.x < half2) ? xb1 : xb2;
    float* sq      = (blockIdx.x < half2) ? sq1 : sq2;
    const int bb   = (blockIdx.x < half2) ? blockIdx.x : blockIdx.x - half2;

    const int wave = threadIdx.x >> 6;
    const int lane = threadIdx.x & 63;
    const int row  = bb * 4 + wave;
    const float4 v = ((const float4*)(x + (size_t)row * KDIM))[lane];
    float s = v.x * v.x + v.y * v.y + v.z * v.z + v.w * v.w;
#pragma unroll
    for (int off = 32; off; off >>= 1) s += __shfl_down(s, off);
    if (lane == 0) sq[row] = s;
    ushort4 o;
    o.x = f2bf_rne(v.x); o.y = f2bf_rne(v.y);
    o.z = f2bf_rne(v.z); o.w = f2bf_rne(v.w);
    ((ushort4*)(xb + (size_t)row * KDIM))[lane] = o;
}

__global__ __launch_bounds__(NTHREADS, 6) void cdist_mfma_kernel(
    const ushort* __restrict__ A,    // x1 bf16, [8192][256]
    const ushort* __restrict__ B,    // x2 bf16, [8192][256]
    const float* __restrict__ sq1,   // ||x1_i||^2
    const float* __restrict__ sq2,   // ||x2_j||^2
    float* __restrict__ out) {       // [8192][8192]
    __shared__ ushort As[TILE * BK];  // 16 KiB, row-major, NO padding
    __shared__ ushort Bs[TILE * BK];  // (global_load_lds needs contiguous lanes)

    // XCD chunking: 8 chunks of 16(bm) x 32(bn) tiles; per-XCD working set
    // A 1 MiB + B 2 MiB = 3 MiB < 4 MiB L2. Bijective (4096 % 8 == 0).
    const int bid = blockIdx.x;
    const int xcd = bid & 7;
    const int cc  = bid >> 3;                      // 0..511
    const int bm  = ((xcd & 3) << 4) | (cc & 15);  // 0..63
    const int bn  = ((xcd >> 2) << 5) | (cc >> 4); // 0..63

    const int tid  = threadIdx.x;
    const int wave = tid >> 6;
    const int lane = tid & 63;
    const int wr = wave >> 2;         // 0..1 -> 64 rows
    const int wc = wave & 3;          // 0..3 -> 32 cols

    // staging lane layout: 8 lanes x 16B cover one 64-elem bf16 row (128 B)
    const int lrow = lane >> 3;       // 0..7 rows within an 8-row chunk
    const int lk   = (lane & 7) * 8;  // bf16 k-offset within row

    v4f acc[4][2];
#pragma unroll
    for (int i = 0; i < 4; ++i)
#pragma unroll
        for (int j = 0; j < 2; ++j) acc[i][j] = (v4f){0.f, 0.f, 0.f, 0.f};

    const int half = lane >> 4;       // 0..3
    const int mrow = lane & 15;       // fragment row/col within 16

    for (int kt = 0; kt < KDIM; kt += BK) {
        __syncthreads();  // previous tile's LDS reads done before overwrite
#pragma unroll
        for (int c = 0; c < 2; ++c) {
            const int rbase = wave * 16 + c * 8;   // 8 rows per wave-call
            const ushort* ga =
                A + (size_t)(bm * TILE + rbase + lrow) * KDIM + kt + lk;
            const ushort* gb =
                B + (size_t)(bn * TILE + rbase + lrow) * KDIM + kt + lk;
            async_load16(ga, &As[rbase * BK]);
            async_load16(gb, &Bs[rbase * BK]);
        }
        __syncthreads();  // drains vmcnt before barrier (compiler-inserted)
#pragma unroll
        for (int kk = 0; kk < BK; kk += 32) {
            v8bf a[4], b[2];
#pragma unroll
            for (int i = 0; i < 4; ++i)
                a[i] = *(const v8bf*)&As[(wr * 64 + i * 16 + mrow) * BK + kk + half * 8];
#pragma unroll
            for (int j = 0; j < 2; ++j)
                b[j] = *(const v8bf*)&Bs[(wc * 32 + j * 16 + mrow) * BK + kk + half * 8];
#pragma unroll
            for (int i = 0; i < 4; ++i)
#pragma unroll
                for (int j = 0; j < 2; ++j)
                    acc[i][j] = __builtin_amdgcn_mfma_f32_16x16x32_bf16(
                        a[i], b[j], acc[i][j], 0, 0, 0);
        }
    }

    // Epilogue: C/D layout col=lane&15, row=(lane>>4)*4+reg (m89/m91 verified)
    const int m0 = bm * TILE + wr * 64;
    const int n0 = bn * TILE + wc * 32;
    float s2v[2];
#pragma unroll
    for (int j = 0; j < 2; ++j) s2v[j] = sq2[n0 + j * 16 + mrow];
#pragma unroll
    for (int i = 0; i < 4; ++i) {
        const int rbase = m0 + i * 16 + half * 4;
        float s1v[4];
#pragma unroll
        for (int r = 0; r < 4; ++r) s1v[r] = sq1[rbase + r];
#pragma unroll
        for (int r = 0; r < 4; ++r) {
            float* op = out + (size_t)(rbase + r) * NROWS + n0 + mrow;
#pragma unroll
            for (int j = 0; j < 2; ++j) {
                const float d2 = s1v[r] + s2v[j] - 2.0f * acc[i][j][r];
                op[j * 16] = sqrtf(fmaxf(d2, 0.0f));
            }
        }
    }
}

extern "C" void kernel_launch(void* const* d_in, const int* in_sizes, int n_in,
                              void* d_out, int out_size, void* d_ws, size_t ws_size,
                              hipStream_t stream) {
    const float* x1 = (const float*)d_in[0];
    const float* x2 = (const float*)d_in[1];
    float* out = (float*)d_out;

    // ws layout: A_bf16 (4 MiB) | B_bf16 (4 MiB) | sq1 (32 KiB) | sq2 (32 KiB)
    ushort* Ab = (ushort*)d_ws;
    ushort* Bb = Ab + (size_t)NROWS * KDIM;
    float* sq1 = (float*)(Bb + (size_t)NROWS * KDIM);
    float* sq2 = sq1 + NROWS;

    cvt_norm_kernel<<<NROWS / 2, 256, 0, stream>>>(x1, x2, Ab, Bb, sq1, sq2);

    // (8192/128)^2 = 4096 blocks, XCD-chunked inside the kernel.
    cdist_mfma_kernel<<<4096, NTHREADS, 0, stream>>>(Ab, Bb, sq1, sq2, out);
}